// Round 1
// baseline (197.974 us; speedup 1.0000x reference)
//
#include <hip/hip_runtime.h>
#include <hip/hip_bf16.h>
#include <cstdint>

// bf16 fragments as 8 x short (4 VGPRs) per cdna_hip_programming.md §3
typedef __attribute__((ext_vector_type(8))) short bf16x8;
typedef __attribute__((ext_vector_type(4))) float f32x4;
typedef __attribute__((ext_vector_type(4))) uint16_t u16x4;

__device__ __forceinline__ uint16_t f2b(float f) {
  union { float f; uint32_t i; } v; v.f = f;
  return (uint16_t)((v.i + 0x7FFFu + ((v.i >> 16) & 1u)) >> 16);  // RNE
}

// async global->LDS, 16B per lane; LDS dest is wave-uniform base + lane*16
#define GLDS16(g, l) __builtin_amdgcn_global_load_lds( \
    (const __attribute__((address_space(1))) void*)(g), \
    (__attribute__((address_space(3))) void*)(l), 16, 0, 0)

// ---------------------------------------------------------------------------
// fp32 -> bf16 convert (RNE) for all three inputs in one launch
// ---------------------------------------------------------------------------
__global__ __launch_bounds__(256) void cvt_all(
    const float* __restrict__ x, const float* __restrict__ wa, const float* __restrict__ wp,
    uint16_t* __restrict__ xb, uint16_t* __restrict__ wab, uint16_t* __restrict__ wpb) {
  const int i = (blockIdx.x * 256 + threadIdx.x) * 4;
  const float* src; uint16_t* dst; int off;
  if (i < 4194304)      { src = x;  dst = xb;  off = i; }
  else if (i < 7340032) { src = wa; dst = wab; off = i - 4194304; }
  else                  { src = wp; dst = wpb; off = i - 7340032; }
  const float4 v = *(const float4*)(src + off);
  u16x4 o;
  o.x = f2b(v.x); o.y = f2b(v.y); o.z = f2b(v.z); o.w = f2b(v.w);
  *(u16x4*)(dst + off) = o;
}

// ---------------------------------------------------------------------------
// C[M,N] = A[M,K] @ B[N,K]^T + bias[N]. A,B bf16, bias fp32, fp32 accumulate.
// BM x 128 block tile, BK=64 (two BK=32 sub-stages per barrier round).
// 4 waves, each (BM/2) x 64. Vectorized epilogue via LDS transpose.
// ---------------------------------------------------------------------------
template <int BM, bool OUT_BF16>
__global__ __launch_bounds__(256) void gemm_bt_bias(
    const uint16_t* __restrict__ A, const uint16_t* __restrict__ B,
    const float* __restrict__ bias, void* __restrict__ Cv,
    int M, int N, int K) {
  constexpr int MI = BM / 32;            // acc rows of 16
  constexpr int CA = BM / 16;            // A chunks per k-half
  constexpr int CPW = (2 * (CA + 8)) / 4;
  constexpr int CT_PITCH = OUT_BF16 ? 72 : 68;
  constexpr size_t CT_BYTES = (size_t)4 * (BM / 2) * CT_PITCH * (OUT_BF16 ? 2 : 4);
  constexpr size_t ST_BYTES = (size_t)(2 * (BM * 32 + 4096)) * 2;
  constexpr size_t LB = CT_BYTES > ST_BYTES ? CT_BYTES : ST_BYTES;
  __shared__ alignas(16) unsigned char ldsb[LB];
  uint16_t* lds = (uint16_t*)ldsb;
  const int offB0 = BM * 32;             // u16 offsets
  const int offA1 = BM * 32 + 4096;
  const int offB1 = 2 * BM * 32 + 4096;

  const int tid = threadIdx.x;
  const int wave = tid >> 6, lane = tid & 63;
  const int q4 = lane >> 4, l16 = lane & 15;
  const int wm = wave >> 1, wn = wave & 1;
  const long blockM = (long)blockIdx.y * BM;
  const long blockN = (long)blockIdx.x * 128;

  f32x4 acc[MI][4] = {};

  for (int k0 = 0; k0 < K; k0 += 64) {
#pragma unroll
    for (int c = 0; c < CPW; ++c) {
      const int id = c * 4 + wave;       // wave-uniform
      const uint16_t* mat; long rowBase; int a, kk, off;
      if (id < CA)               { mat = A; rowBase = blockM; a = id;            kk = k0;      off = 0; }
      else if (id < CA + 8)      { mat = B; rowBase = blockN; a = id - CA;       kk = k0;      off = offB0; }
      else if (id < 2 * CA + 8)  { mat = A; rowBase = blockM; a = id - CA - 8;   kk = k0 + 32; off = offA1; }
      else                       { mat = B; rowBase = blockN; a = id - 2*CA - 8; kk = k0 + 32; off = offB1; }
      const int flat = a * 64 + lane;
      const int row = flat >> 2, seg = flat & 3;
      GLDS16(mat + (rowBase + row) * (long)K + kk + seg * 8, lds + off + a * 512);
    }
    __syncthreads();
#pragma unroll
    for (int h = 0; h < 2; ++h) {
      const uint16_t* Ah = lds + (h ? offA1 : 0);
      const uint16_t* Bh = lds + (h ? offB1 : offB0);
      bf16x8 af[MI], bfr[4];
#pragma unroll
      for (int i = 0; i < MI; ++i)
        af[i] = *(const bf16x8*)&Ah[(wm * (BM / 2) + i * 16 + l16) * 32 + q4 * 8];
#pragma unroll
      for (int j = 0; j < 4; ++j)
        bfr[j] = *(const bf16x8*)&Bh[(wn * 64 + j * 16 + l16) * 32 + q4 * 8];
#pragma unroll
      for (int i = 0; i < MI; ++i)
#pragma unroll
        for (int j = 0; j < 4; ++j)
          acc[i][j] = __builtin_amdgcn_mfma_f32_16x16x32_bf16(af[i], bfr[j], acc[i][j], 0, 0, 0);
    }
    __syncthreads();
  }

  // epilogue: acc (C/D layout: col=l16, row=q4*4+r) -> per-wave LDS tile -> vector stores
  if (OUT_BF16) {
    uint16_t* ct = lds + wave * (BM / 2) * 72;
#pragma unroll
    for (int j = 0; j < 4; ++j) {
      const float bv = bias[blockN + wn * 64 + j * 16 + l16];
#pragma unroll
      for (int i = 0; i < MI; ++i)
#pragma unroll
        for (int r = 0; r < 4; ++r)
          ct[(i * 16 + q4 * 4 + r) * 72 + j * 16 + l16] = f2b(acc[i][j][r] + bv);
    }
    __syncthreads();
    uint16_t* Cb = (uint16_t*)Cv;
#pragma unroll
    for (int st = 0; st < BM / 16; ++st) {
      const int flat = st * 64 + lane;
      const int row = flat >> 3, seg = flat & 7;
      const bf16x8 v = *(const bf16x8*)&ct[row * 72 + seg * 8];
      *(bf16x8*)&Cb[(blockM + wm * (BM / 2) + row) * (long)N + blockN + wn * 64 + seg * 8] = v;
    }
  } else {
    float* ct = (float*)ldsb + wave * (BM / 2) * 68;
#pragma unroll
    for (int j = 0; j < 4; ++j) {
      const float bv = bias[blockN + wn * 64 + j * 16 + l16];
#pragma unroll
      for (int i = 0; i < MI; ++i)
#pragma unroll
        for (int r = 0; r < 4; ++r)
          ct[(i * 16 + q4 * 4 + r) * 68 + j * 16 + l16] = acc[i][j][r] + bv;
    }
    __syncthreads();
    float* Cb = (float*)Cv;
#pragma unroll
    for (int st = 0; st < BM / 8; ++st) {
      const int flat = st * 64 + lane;
      const int row = flat >> 4, seg = flat & 15;
      const f32x4 v = *(const f32x4*)&ct[row * 68 + seg * 4];
      *(f32x4*)&Cb[(blockM + wm * (BM / 2) + row) * (long)N + blockN + wn * 64 + seg * 4] = v;
    }
  }
}

// ---------------------------------------------------------------------------
// Flash-style causal attention, S^T formulation.
// Grid: 1024 blocks; block (sidx,bh) processes q-strip qb = 31-sidx (big
// strips dispatched first, 1-tile strips backfill the tail). 4 blocks/CU
// steady (LDS 35.8KB x 4 = 143KB). Next tile's K/V prefetched into VGPRs.
// ---------------------------------------------------------------------------
__global__ __launch_bounds__(256, 4) void attn_flash(
    const uint16_t* __restrict__ kqv, uint16_t* __restrict__ attn) {
  constexpr int T = 2048, C = 1024, C3 = 3072;
  __shared__ uint16_t KP[128 * 72];   // Kt [key][d] pitch 72; Pt overlays after S3
  __shared__ uint16_t Vt[64 * 136];   // V^T [d][key'] pitch 136, key' = (key+16*(d>>3))&127
  uint32_t* VtW = (uint32_t*)Vt;      // pitch 68 dwords

  const int tid = threadIdx.x;
  const int wave = tid >> 6, lane = tid & 63;
  const int q4 = lane >> 4, l16 = lane & 15;
  const int sidx = blockIdx.x >> 5, bh = blockIdx.x & 31;
  const int b = bh >> 4, h = bh & 15;
  const size_t base = (size_t)b * T * C3;
  const int hD = h * 64;

  uint16_t* Pt = &KP[wave * 2176];    // 16 x 136 per wave

  // loop-invariant staging coords
  const int tr = tid >> 3, kch = tid & 7;
  const float sc = 0.125f * 1.4426950408889634f;  // D^-0.5 * log2(e)

  const int qb = 31 - sidx;           // big strips first
  const int nkt = (qb >> 1) + 1;
  const int qrow = qb * 64 + wave * 16 + l16;
  const bf16x8 qf0 = *(const bf16x8*)&kqv[base + (size_t)qrow * C3 + C + hD + q4 * 8];
  const bf16x8 qf1 = *(const bf16x8*)&kqv[base + (size_t)qrow * C3 + C + hD + 32 + q4 * 8];

  f32x4 o[4] = {};                  // O[q=q4*4+r][d=d4*16+l16]
  float m_i = -1e30f, l_i = 0.f;

  // prefetch tile 0 into VGPRs
  bf16x8 pk[4], pv0[2], pv1[2];
#pragma unroll
  for (int rr = 0; rr < 4; ++rr)
    pk[rr] = *(const bf16x8*)&kqv[base + (size_t)(rr * 32 + tr) * C3 + hD + kch * 8];
#pragma unroll
  for (int s2 = 0; s2 < 2; ++s2) {
    const size_t g = base + (size_t)(2 * (s2 * 32 + tr)) * C3 + 2 * C + hD + kch * 8;
    pv0[s2] = *(const bf16x8*)&kqv[g];
    pv1[s2] = *(const bf16x8*)&kqv[g + C3];
  }

  for (int kt = 0; kt < nkt; ++kt) {
    const int kbase = kt * 128;
    __syncthreads();   // S1: prior PV reads done
    // stage K from prefetch regs (b128, LDS addr loop-invariant)
#pragma unroll
    for (int rr = 0; rr < 4; ++rr)
      *(bf16x8*)&KP[(rr * 32 + tr) * 72 + kch * 8] = pk[rr];
    // stage V transposed: v_perm pack key-pairs, rot-16 swizzle (2-way free)
#pragma unroll
    for (int s2 = 0; s2 < 2; ++s2) {
      const int colw = ((s2 * 32 + tr) + 8 * kch) & 63;
      const uint32_t* a0 = (const uint32_t*)&pv0[s2];
      const uint32_t* a1 = (const uint32_t*)&pv1[s2];
#pragma unroll
      for (int i = 0; i < 8; ++i) {
        const uint32_t w = (i & 1)
            ? __builtin_amdgcn_perm(a1[i >> 1], a0[i >> 1], 0x07060302u)
            : __builtin_amdgcn_perm(a1[i >> 1], a0[i >> 1], 0x05040100u);
        VtW[(kch * 8 + i) * 68 + colw] = w;
      }
    }
    __syncthreads();   // S2: staging visible
    // prefetch next tile (loads in flight across the compute phase)
    if (kt + 1 < nkt) {
      const int kb = kbase + 128;
#pragma unroll
      for (int rr = 0; rr < 4; ++rr)
        pk[rr] = *(const bf16x8*)&kqv[base + (size_t)(kb + rr * 32 + tr) * C3 + hD + kch * 8];
#pragma unroll
      for (int s2 = 0; s2 < 2; ++s2) {
        const size_t g = base + (size_t)(kb + 2 * (s2 * 32 + tr)) * C3 + 2 * C + hD + kch * 8;
        pv0[s2] = *(const bf16x8*)&kqv[g];
        pv1[s2] = *(const bf16x8*)&kqv[g + C3];
      }
    }
    // S^T = K·Q^T : lane holds S^T[key=16nk+q4*4+r][q=l16]
    f32x4 s[8];
#pragma unroll
    for (int nk = 0; nk < 8; ++nk) {
      f32x4 z = {};
      const bf16x8 kf0 = *(const bf16x8*)&KP[(nk * 16 + l16) * 72 + q4 * 8];
      const bf16x8 kf1 = *(const bf16x8*)&KP[(nk * 16 + l16) * 72 + 32 + q4 * 8];
      z = __builtin_amdgcn_mfma_f32_16x16x32_bf16(kf0, qf0, z, 0, 0, 0);
      z = __builtin_amdgcn_mfma_f32_16x16x32_bf16(kf1, qf1, z, 0, 0, 0);
      s[nk] = z;
    }
    // causal mask only on diagonal tiles (wave-uniform branch)
    if (kbase + 127 > qb * 64 + wave * 16) {
#pragma unroll
      for (int nk = 0; nk < 8; ++nk) {
        const int key0 = kbase + nk * 16 + q4 * 4;
#pragma unroll
        for (int r = 0; r < 4; ++r)
          s[nk][r] = (key0 + r <= qrow) ? s[nk][r] : -1e30f;
      }
    }
    // online softmax (per-lane over 32 keys + 2 shuffles)
    float mloc = s[0][0];
#pragma unroll
    for (int nk = 0; nk < 8; ++nk)
#pragma unroll
      for (int r = 0; r < 4; ++r) mloc = fmaxf(mloc, s[nk][r]);
    mloc = fmaxf(mloc, __shfl_xor(mloc, 16, 64));
    mloc = fmaxf(mloc, __shfl_xor(mloc, 32, 64));
    const float mnew = fmaxf(m_i, mloc * sc);
    const float alpha = exp2f(m_i - mnew);
    const bool mchg = mnew > m_i;
    m_i = mnew;
    float rs = 0.f;
#pragma unroll
    for (int nk = 0; nk < 8; ++nk)
#pragma unroll
      for (int r = 0; r < 4; ++r) {
        const float pe = exp2f(fmaf(s[nk][r], sc, -mnew));
        s[nk][r] = pe;
        rs += pe;
      }
    rs += __shfl_xor(rs, 16, 64);
    rs += __shfl_xor(rs, 32, 64);
    l_i = l_i * alpha + rs;
    if (__any(mchg)) {   // skip O-rescale when every row's max is unchanged
#pragma unroll
      for (int r = 0; r < 4; ++r) {
        const float ar = __shfl(alpha, q4 * 4 + r, 64);
#pragma unroll
        for (int d4 = 0; d4 < 4; ++d4) o[d4][r] *= ar;
      }
    }
    __syncthreads();   // S3: Kt reads done -> Pt may overwrite KP
    // P write: packed bf16 pairs, one b64 per nk
#pragma unroll
    for (int nk = 0; nk < 8; ++nk) {
      union { __hip_bfloat162 h2; uint32_t u; } c01, c23;
      c01.h2 = __float22bfloat162_rn(make_float2(s[nk][0], s[nk][1]));
      c23.h2 = __float22bfloat162_rn(make_float2(s[nk][2], s[nk][3]));
      uint2 pkw; pkw.x = c01.u; pkw.y = c23.u;
      *(uint2*)&Pt[l16 * 136 + nk * 16 + q4 * 4] = pkw;
    }
    __syncthreads();   // S4: Pt visible
    // O += P·V
#pragma unroll
    for (int ks = 0; ks < 4; ++ks) {
      const bf16x8 pf = *(const bf16x8*)&Pt[l16 * 136 + ks * 32 + q4 * 8];
#pragma unroll
      for (int d4 = 0; d4 < 4; ++d4) {
        const int d = d4 * 16 + l16;
        const int col = (ks * 32 + q4 * 8 + 16 * (d >> 3)) & 127;
        const bf16x8 vf = *(const bf16x8*)&Vt[d * 136 + col];
        o[d4] = __builtin_amdgcn_mfma_f32_16x16x32_bf16(pf, vf, o[d4], 0, 0, 0);
      }
    }
  }
  // epilogue
  const size_t obase = (size_t)b * T * C;
  const float linv = 1.0f / l_i;
#pragma unroll
  for (int r = 0; r < 4; ++r) {
    const float lr = __shfl(linv, q4 * 4 + r, 64);
    const int q = qb * 64 + wave * 16 + q4 * 4 + r;
    const size_t rowoff = obase + (size_t)q * C + hD;
#pragma unroll
    for (int d4 = 0; d4 < 4; ++d4)
      attn[rowoff + d4 * 16 + l16] = f2b(o[d4][r] * lr);
  }
}

extern "C" void kernel_launch(void* const* d_in, const int* in_sizes, int n_in,
                              void* d_out, int out_size, void* d_ws, size_t ws_size,
                              hipStream_t stream) {
  const float* x      = (const float*)d_in[0];  // (2,2048,1024) fp32
  const float* w_attn = (const float*)d_in[1];  // (3072,1024)  fp32
  const float* b_attn = (const float*)d_in[2];  // (3072,)      fp32
  const float* w_proj = (const float*)d_in[3];  // (1024,1024)  fp32
  const float* b_proj = (const float*)d_in[4];  // (1024,)      fp32
  float* out = (float*)d_out;                   // (2,2048,1024) fp32

  // ws layout (bf16): xb | wab | wpb | kqv | attnb
  uint16_t* xb    = (uint16_t*)d_ws;                     // 4096*1024
  uint16_t* wab   = xb  + (size_t)4096 * 1024;           // 3072*1024
  uint16_t* wpb   = wab + (size_t)3072 * 1024;           // 1024*1024
  uint16_t* kqv   = wpb + (size_t)1024 * 1024;           // 4096*3072
  uint16_t* attnb = kqv + (size_t)4096 * 3072;           // 4096*1024

  dim3 blk(256, 1, 1);
  hipLaunchKernelGGL(cvt_all, dim3(8192), blk, 0, stream, x, w_attn, w_proj, xb, wab, wpb);

  hipLaunchKernelGGL((gemm_bt_bias<128, true>), dim3(3072 / 128, 4096 / 128, 1), blk, 0, stream,
                     xb, wab, b_attn, (void*)kqv, 4096, 3072, 1024);
  hipLaunchKernelGGL(attn_flash, dim3(1024, 1, 1), blk, 0, stream, kqv, attnb);
  hipLaunchKernelGGL((gemm_bt_bias<64, false>), dim3(1024 / 128, 4096 / 64, 1), blk, 0, stream,
                     attnb, wpb, b_proj, (void*)out, 4096, 1024, 1024);
}